// Round 5
// baseline (303.306 us; speedup 1.0000x reference)
//
#include <hip/hip_runtime.h>
#include <math.h>

#define ACC_BITS 23

typedef float f32x4 __attribute__((ext_vector_type(4)));

#define TPB   256
#define VPT   8                      // float4 vectors per thread (R5: 4 -> 8)
#define TILE  (TPB * VPT)            // 2048 float4 per block

// Fixed-point requant parameters, computed in-register per thread (uniform).
struct QP {
    float scale;
    int   fast;                       // 1 => 24-bit fast path valid
    int   nmx_hi, nmx_lo, Kx, srx12;  // x:  nm split 12/12, K=2^(sr-1), sr-12
    int   nmi_hi, nmi_lo, Ki, sri12;  // id: same
    long long nm_x64, nm_i64;         // generic fallback
    int   e_x, e_i;
};

// Bit-exact vs reference: fp32 scale divide, fp64 ns, frexp, round-half-even
// mantissa quantization (rint == jnp.round). Runs under the in-flight loads.
__device__ __forceinline__ QP compute_qparams(float pre, float idsf,
                                              float xmn, float xmx) {
    QP q;
    float s     = fmaxf(fmaxf(fabsf(xmn), fabsf(xmx)), 1e-8f);
    float scale = s / 127.0f;

    double s64  = (double)scale;
    double ns_x = (double)pre  / s64;
    double ns_i = (double)idsf / s64;

    int e_x, e_i;
    double m_x = frexp(ns_x, &e_x);           // m in [0.5,1)
    double m_i = frexp(ns_i, &e_i);
    long long nm_x = (long long)rint(m_x * 8388608.0);   // round-half-even
    long long nm_i = (long long)rint(m_i * 8388608.0);

    q.scale  = scale;
    q.nm_x64 = nm_x;  q.e_x = e_x;
    q.nm_i64 = nm_i;  q.e_i = e_i;

    // Normalize nm == 2^23 -> (2^22, e+1). Result-identical (R3 note, prior
    // session: the rounded numerator is always even in that case).
    long long ax = nm_x, ai = nm_i;
    int ex = e_x, ei = e_i;
    if (ax == (1LL << 23)) { ax >>= 1; ex += 1; }
    if (ai == (1LL << 23)) { ai >>= 1; ei += 1; }
    int sr_x = ACC_BITS - ex, sr_i = ACC_BITS - ei;

    q.fast = (ax > 0) && (ax < (1LL << 23)) &&
             (ai > 0) && (ai < (1LL << 23)) &&
             (sr_x >= 12) && (sr_x <= 30) && (sr_i >= 12) && (sr_i <= 30);
    q.nmx_hi = (int)(ax >> 12); q.nmx_lo = (int)(ax & 0xFFF);
    q.nmi_hi = (int)(ai >> 12); q.nmi_lo = (int)(ai & 0xFFF);
    q.Kx = q.fast ? (1 << (sr_x - 1)) : 0;
    q.Ki = q.fast ? (1 << (sr_i - 1)) : 0;
    q.srx12 = sr_x - 12;
    q.sri12 = sr_i - 12;
    return q;
}

// Generic bit-exact replica (fallback + tail).
__device__ __forceinline__ long long fixed_point_mul64(long long xi, long long nm, int e) {
    long long tmp = xi * nm;
    if (e - ACC_BITS >= 0) {
        return tmp << (e - ACC_BITS);
    } else {
        int sr = ACC_BITS - e;
        long long nudge = (1LL << (sr - 1)) - (long long)(tmp < 0);
        return (tmp + nudge) >> sr;
    }
}

// Full-rate 24-bit-multiply fixed-point mul (bit-exact for |xi|<2^19,
// 0<nm<2^23, 12<=sr<=30; R3 derivation from prior session).
__device__ __forceinline__ int fpm24(int xi, int nm_hi, int nm_lo, int K, int sr12) {
    int bit = (int)((unsigned)xi >> 31);
    int B = (__mul24(xi, nm_lo) + K - bit) >> 12;
    int A = __mul24(xi, nm_hi);
    return (A + B) >> sr12;
}

// R4 post-mortem: nt LOADS were the unlock (112 -> <=78 us). FETCH_SIZE's
// stable 134 MB was real L3 hits — allocate/victim churn on a 402 MB cyclic
// working set through 256 MB L3 was the throttle; no-allocate reads remove
// it. Stores MUST stay cached (R1: nt stores +13 us — L2 write-combining;
// harness fills hit 6.8 TB/s with cached stores).
// R5 change: VPT 4 -> 8. Doubles per-wave contiguous footprint per stream
// (better DRAM page locality per burst), halves total waves (less turnover
// tail). 16 loads in flight/wave; VGPR ~90 -> 5 waves/SIMD, which R2/R3
// proved is not the limiter.
__global__ void __launch_bounds__(TPB)
quantact_fused(const f32x4* __restrict__ x,
               const f32x4* __restrict__ idn,
               f32x4* __restrict__ out,
               float* __restrict__ out_scale,
               const float* __restrict__ pre_sf,
               const float* __restrict__ id_sf,
               const float* __restrict__ xminp,
               const float* __restrict__ xmaxp,
               int n4, int n)
{
    const int base = blockIdx.x * TILE + (int)threadIdx.x;
    const bool full = (base + (VPT - 1) * TPB) < n4;

    // Uniform scalar loads (s_load, lgkmcnt) — issue first.
    const float pre  = pre_sf[0];
    const float idsf = id_sf[0];
    const float xmn  = xminp[0];
    const float xmx  = xmaxp[0];

    // All 16 vector loads, pairwise x/id interleaved, nontemporal
    // (no-allocate: zero reuse, keep them out of L2/L3 entirely).
    f32x4 xv[VPT], iv[VPT];
    if (full) {
        #pragma unroll
        for (int k = 0; k < VPT; ++k) {
            xv[k] = __builtin_nontemporal_load(&x[base + k * TPB]);
            iv[k] = __builtin_nontemporal_load(&idn[base + k * TPB]);
        }
    }
    // Nothing may hoist above; no load may sink below.
    __builtin_amdgcn_sched_barrier(0);

    const QP q = compute_qparams(pre, idsf, xmn, xmx);
    const float scale = q.scale;

    if (blockIdx.x == 0 && threadIdx.x == 0) *out_scale = scale;  // tuple out 1

    if (q.fast) {
        const int nmx_hi = q.nmx_hi, nmx_lo = q.nmx_lo, Kx = q.Kx, srx = q.srx12;
        const int nmi_hi = q.nmi_hi, nmi_lo = q.nmi_lo, Ki = q.Ki, sri = q.sri12;

        if (full) {
            // Per-k compute + immediate (cached) store: frees registers as
            // loads drain; store issue overlaps the remaining load waits.
            #pragma unroll
            for (int k = 0; k < VPT; ++k) {
                f32x4 ov;
                #pragma unroll
                for (int c = 0; c < 4; ++c) {
                    int o = fpm24((int)xv[k][c], nmx_hi, nmx_lo, Kx, srx)
                          + fpm24((int)iv[k][c], nmi_hi, nmi_lo, Ki, sri);
                    o = o < -128 ? -128 : (o > 127 ? 127 : o);   // v_med3_i32
                    ov[c] = (float)o * scale;
                }
                out[base + k * TPB] = ov;
            }
        } else {
            #pragma unroll
            for (int k = 0; k < VPT; ++k) {
                int i = base + k * TPB;
                if (i < n4) {
                    f32x4 xw = __builtin_nontemporal_load(&x[i]);
                    f32x4 iw = __builtin_nontemporal_load(&idn[i]);
                    f32x4 ov;
                    #pragma unroll
                    for (int c = 0; c < 4; ++c) {
                        int o = fpm24((int)xw[c], nmx_hi, nmx_lo, Kx, srx)
                              + fpm24((int)iw[c], nmi_hi, nmi_lo, Ki, sri);
                        o = o < -128 ? -128 : (o > 127 ? 127 : o);
                        ov[c] = (float)o * scale;
                    }
                    out[i] = ov;
                }
            }
        }
    } else {
        // Generic path: exact 64-bit replica of the reference branches.
        const long long nm64_x = q.nm_x64, nm64_i = q.nm_i64;
        const int e_x = q.e_x, e_i = q.e_i;
        #pragma unroll
        for (int k = 0; k < VPT; ++k) {
            int i = base + k * TPB;
            if (i < n4) {
                f32x4 xw, iw, ov;
                if (full) { xw = xv[k]; iw = iv[k]; }
                else      { xw = x[i];  iw = idn[i]; }
                #pragma unroll
                for (int c = 0; c < 4; ++c) {
                    long long o = fixed_point_mul64((long long)xw[c], nm64_x, e_x)
                                + fixed_point_mul64((long long)iw[c], nm64_i, e_i);
                    o = o < -128 ? -128 : (o > 127 ? 127 : o);
                    ov[c] = (float)(int)o * scale;
                }
                out[i] = ov;
            }
        }
    }

    // scalar tail for n % 4 != 0 (not hit at this shape)
    if (blockIdx.x == 0) {
        const float* xs  = (const float*)x;
        const float* is_ = (const float*)idn;
        float* os = (float*)out;
        const long long nm64_x = q.nm_x64, nm64_i = q.nm_i64;
        const int e_x = q.e_x, e_i = q.e_i;
        for (int j = n4 * 4 + (int)threadIdx.x; j < n; j += TPB) {
            long long o = fixed_point_mul64((long long)xs[j], nm64_x, e_x)
                        + fixed_point_mul64((long long)is_[j], nm64_i, e_i);
            o = o < -128 ? -128 : (o > 127 ? 127 : o);
            os[j] = (float)(int)o * scale;
        }
    }
}

extern "C" void kernel_launch(void* const* d_in, const int* in_sizes, int n_in,
                              void* d_out, int out_size, void* d_ws, size_t ws_size,
                              hipStream_t stream) {
    const f32x4* x      = (const f32x4*)d_in[0];
    const f32x4* idn    = (const f32x4*)d_in[1];
    const float* pre_sf = (const float*)d_in[2];
    const float* id_sf  = (const float*)d_in[3];
    const float* xmin   = (const float*)d_in[4];
    const float* xmax   = (const float*)d_in[5];

    int n  = in_sizes[0];          // 33,554,432
    int n4 = n / 4;                // 8,388,608 float4

    float* out       = (float*)d_out;
    float* out_scale = out + n;    // tuple output 1 (flat-concatenated)

    int grid = (n4 + TILE - 1) / TILE;   // 4096 blocks, one-shot
    if (grid < 1) grid = 1;
    quantact_fused<<<grid, TPB, 0, stream>>>(x, idn, (f32x4*)out, out_scale,
                                             pre_sf, id_sf, xmin, xmax, n4, n);
}

// Round 6
// 298.049 us; speedup vs baseline: 1.0176x; 1.0176x over previous
//
#include <hip/hip_runtime.h>
#include <math.h>

#define ACC_BITS 23

typedef float f32x4 __attribute__((ext_vector_type(4)));

#define TPB   256
#define VPT   4                      // float4 vectors per thread (R5's 8 regressed ~5us; 4 is optimal)
#define TILE  (TPB * VPT)            // 1024 float4 per block

// Fixed-point requant parameters, computed in-register per thread (uniform).
struct QP {
    float scale;
    int   fast;                       // 1 => 24-bit fast path valid
    int   nmx_hi, nmx_lo, Kx, srx12;  // x:  nm split 12/12, K=2^(sr-1), sr-12
    int   nmi_hi, nmi_lo, Ki, sri12;  // id: same
    long long nm_x64, nm_i64;         // generic fallback
    int   e_x, e_i;
};

// Bit-exact vs reference: fp32 scale divide, fp64 ns, frexp, round-half-even
// mantissa quantization (rint == jnp.round). Runs under the 8 in-flight loads.
__device__ __forceinline__ QP compute_qparams(float pre, float idsf,
                                              float xmn, float xmx) {
    QP q;
    float s     = fmaxf(fmaxf(fabsf(xmn), fabsf(xmx)), 1e-8f);
    float scale = s / 127.0f;

    double s64  = (double)scale;
    double ns_x = (double)pre  / s64;
    double ns_i = (double)idsf / s64;

    int e_x, e_i;
    double m_x = frexp(ns_x, &e_x);           // m in [0.5,1)
    double m_i = frexp(ns_i, &e_i);
    long long nm_x = (long long)rint(m_x * 8388608.0);   // round-half-even
    long long nm_i = (long long)rint(m_i * 8388608.0);

    q.scale  = scale;
    q.nm_x64 = nm_x;  q.e_x = e_x;
    q.nm_i64 = nm_i;  q.e_i = e_i;

    // Normalize nm == 2^23 -> (2^22, e+1). Result-identical (R3 note, prior
    // session: the rounded numerator is always even in that case).
    long long ax = nm_x, ai = nm_i;
    int ex = e_x, ei = e_i;
    if (ax == (1LL << 23)) { ax >>= 1; ex += 1; }
    if (ai == (1LL << 23)) { ai >>= 1; ei += 1; }
    int sr_x = ACC_BITS - ex, sr_i = ACC_BITS - ei;

    q.fast = (ax > 0) && (ax < (1LL << 23)) &&
             (ai > 0) && (ai < (1LL << 23)) &&
             (sr_x >= 12) && (sr_x <= 30) && (sr_i >= 12) && (sr_i <= 30);
    q.nmx_hi = (int)(ax >> 12); q.nmx_lo = (int)(ax & 0xFFF);
    q.nmi_hi = (int)(ai >> 12); q.nmi_lo = (int)(ai & 0xFFF);
    q.Kx = q.fast ? (1 << (sr_x - 1)) : 0;
    q.Ki = q.fast ? (1 << (sr_i - 1)) : 0;
    q.srx12 = sr_x - 12;
    q.sri12 = sr_i - 12;
    return q;
}

// Generic bit-exact replica (fallback + tail).
__device__ __forceinline__ long long fixed_point_mul64(long long xi, long long nm, int e) {
    long long tmp = xi * nm;
    if (e - ACC_BITS >= 0) {
        return tmp << (e - ACC_BITS);
    } else {
        int sr = ACC_BITS - e;
        long long nudge = (1LL << (sr - 1)) - (long long)(tmp < 0);
        return (tmp + nudge) >> sr;
    }
}

// Full-rate 24-bit-multiply fixed-point mul (bit-exact for |xi|<2^19,
// 0<nm<2^23, 12<=sr<=30; R3 derivation from prior session).
__device__ __forceinline__ int fpm24(int xi, int nm_hi, int nm_lo, int K, int sr12) {
    int bit = (int)((unsigned)xi >> 31);
    int B = (__mul24(xi, nm_lo) + K - bit) >> 12;
    int A = __mul24(xi, nm_hi);
    return (A + B) >> sr12;
}

// FINAL (== R4 config, best measured: headline 298.5 us, kernel <=78 us).
// Session ledger:
//  - nt LOADS: the unlock (112 -> <=78 us). FETCH_SIZE's stable 134 MB was
//    real L3 hits; allocate/victim churn of the 402 MB cyclic working set
//    through 256 MB L3 was the throttle. No-allocate reads remove it.
//  - Stores stay CACHED (R1: nt stores +13 us — kills L2 write-combining).
//  - One-shot 8-deep load burst + sched_barrier; fused scalar qparams under
//    the load shadow (R2).
//  - Refuted: deeper MLP (R2), persistence/double-buffer (R3), VPT=8 (R5).
// Remaining gap to the 6.8 TB/s pure-fill rate is the 2-read+1-write
// stream-mix cost; ~59-64 us is the floor for 402 MB mandatory traffic.
__global__ void __launch_bounds__(TPB)
quantact_fused(const f32x4* __restrict__ x,
               const f32x4* __restrict__ idn,
               f32x4* __restrict__ out,
               float* __restrict__ out_scale,
               const float* __restrict__ pre_sf,
               const float* __restrict__ id_sf,
               const float* __restrict__ xminp,
               const float* __restrict__ xmaxp,
               int n4, int n)
{
    const int base = blockIdx.x * TILE + (int)threadIdx.x;
    const bool full = (base + (VPT - 1) * TPB) < n4;

    // Uniform scalar loads (s_load, lgkmcnt) — issue first.
    const float pre  = pre_sf[0];
    const float idsf = id_sf[0];
    const float xmn  = xminp[0];
    const float xmx  = xmaxp[0];

    // All 8 vector loads, pairwise x/id interleaved, nontemporal
    // (no-allocate: zero reuse, keep them out of L2/L3 entirely).
    f32x4 xv[VPT], iv[VPT];
    if (full) {
        #pragma unroll
        for (int k = 0; k < VPT; ++k) {
            xv[k] = __builtin_nontemporal_load(&x[base + k * TPB]);
            iv[k] = __builtin_nontemporal_load(&idn[base + k * TPB]);
        }
    }
    // Nothing may hoist above; no load may sink below.
    __builtin_amdgcn_sched_barrier(0);

    const QP q = compute_qparams(pre, idsf, xmn, xmx);
    const float scale = q.scale;

    if (blockIdx.x == 0 && threadIdx.x == 0) *out_scale = scale;  // tuple out 1

    if (q.fast) {
        const int nmx_hi = q.nmx_hi, nmx_lo = q.nmx_lo, Kx = q.Kx, srx = q.srx12;
        const int nmi_hi = q.nmi_hi, nmi_lo = q.nmi_lo, Ki = q.Ki, sri = q.sri12;

        if (full) {
            // Per-k compute + immediate (cached) store: frees registers as
            // loads drain; store issue overlaps the remaining load waits.
            #pragma unroll
            for (int k = 0; k < VPT; ++k) {
                f32x4 ov;
                #pragma unroll
                for (int c = 0; c < 4; ++c) {
                    int o = fpm24((int)xv[k][c], nmx_hi, nmx_lo, Kx, srx)
                          + fpm24((int)iv[k][c], nmi_hi, nmi_lo, Ki, sri);
                    o = o < -128 ? -128 : (o > 127 ? 127 : o);   // v_med3_i32
                    ov[c] = (float)o * scale;
                }
                out[base + k * TPB] = ov;
            }
        } else {
            #pragma unroll
            for (int k = 0; k < VPT; ++k) {
                int i = base + k * TPB;
                if (i < n4) {
                    f32x4 xw = __builtin_nontemporal_load(&x[i]);
                    f32x4 iw = __builtin_nontemporal_load(&idn[i]);
                    f32x4 ov;
                    #pragma unroll
                    for (int c = 0; c < 4; ++c) {
                        int o = fpm24((int)xw[c], nmx_hi, nmx_lo, Kx, srx)
                              + fpm24((int)iw[c], nmi_hi, nmi_lo, Ki, sri);
                        o = o < -128 ? -128 : (o > 127 ? 127 : o);
                        ov[c] = (float)o * scale;
                    }
                    out[i] = ov;
                }
            }
        }
    } else {
        // Generic path: exact 64-bit replica of the reference branches.
        const long long nm64_x = q.nm_x64, nm64_i = q.nm_i64;
        const int e_x = q.e_x, e_i = q.e_i;
        #pragma unroll
        for (int k = 0; k < VPT; ++k) {
            int i = base + k * TPB;
            if (i < n4) {
                f32x4 xw, iw, ov;
                if (full) { xw = xv[k]; iw = iv[k]; }
                else      { xw = x[i];  iw = idn[i]; }
                #pragma unroll
                for (int c = 0; c < 4; ++c) {
                    long long o = fixed_point_mul64((long long)xw[c], nm64_x, e_x)
                                + fixed_point_mul64((long long)iw[c], nm64_i, e_i);
                    o = o < -128 ? -128 : (o > 127 ? 127 : o);
                    ov[c] = (float)(int)o * scale;
                }
                out[i] = ov;
            }
        }
    }

    // scalar tail for n % 4 != 0 (not hit at this shape)
    if (blockIdx.x == 0) {
        const float* xs  = (const float*)x;
        const float* is_ = (const float*)idn;
        float* os = (float*)out;
        const long long nm64_x = q.nm_x64, nm64_i = q.nm_i64;
        const int e_x = q.e_x, e_i = q.e_i;
        for (int j = n4 * 4 + (int)threadIdx.x; j < n; j += TPB) {
            long long o = fixed_point_mul64((long long)xs[j], nm64_x, e_x)
                        + fixed_point_mul64((long long)is_[j], nm64_i, e_i);
            o = o < -128 ? -128 : (o > 127 ? 127 : o);
            os[j] = (float)(int)o * scale;
        }
    }
}

extern "C" void kernel_launch(void* const* d_in, const int* in_sizes, int n_in,
                              void* d_out, int out_size, void* d_ws, size_t ws_size,
                              hipStream_t stream) {
    const f32x4* x      = (const f32x4*)d_in[0];
    const f32x4* idn    = (const f32x4*)d_in[1];
    const float* pre_sf = (const float*)d_in[2];
    const float* id_sf  = (const float*)d_in[3];
    const float* xmin   = (const float*)d_in[4];
    const float* xmax   = (const float*)d_in[5];

    int n  = in_sizes[0];          // 33,554,432
    int n4 = n / 4;                // 8,388,608 float4

    float* out       = (float*)d_out;
    float* out_scale = out + n;    // tuple output 1 (flat-concatenated)

    int grid = (n4 + TILE - 1) / TILE;   // 8192 blocks, one-shot
    if (grid < 1) grid = 1;
    quantact_fused<<<grid, TPB, 0, stream>>>(x, idn, (f32x4*)out, out_scale,
                                             pre_sf, id_sf, xmin, xmax, n4, n);
}